// Round 4
// baseline (1041.678 us; speedup 1.0000x reference)
//
#include <hip/hip_runtime.h>
#include <hip/hip_bf16.h>
#include <math.h>

#define BROWS 32768
#define NNB   8
#define DIN   256
#define DH    512
#define DOUT  256
#define MROWS 128   // rows per block (1 block per CU, grid 256)
#define CH    32    // DH cols per chunk
#define NCHUNK 16

typedef __attribute__((ext_vector_type(8))) short bfrag;   // 8 x bf16
typedef __attribute__((ext_vector_type(4))) float ffrag;   // MFMA accumulator
typedef __attribute__((ext_vector_type(4))) float f4v;

__device__ __forceinline__ short f2bf(float f) {
    union { float f; unsigned u; } v; v.f = f;
    unsigned r = v.u + 0x7fffu + ((v.u >> 16) & 1u);   // RNE
    return (short)(r >> 16);
}
__device__ __forceinline__ float bf2f(short s) {
    union { float f; unsigned u; } v;
    v.u = ((unsigned)(unsigned short)s) << 16;
    return v.f;
}

// W1 prep: chunk-major, frag-transposed, gamma-folded.
// dst[c*8192 + (j*32+r)*8 + e] = bf16(W1[8j+e][32c+r] * g[8j+e])
// => stage1 B-frag loads are lane-contiguous 16B (fully coalesced, L1-friendly).
__global__ void w1prep(const float* __restrict__ W1, const float* __restrict__ g,
                       short* __restrict__ dst) {
    const int c = blockIdx.x;
    const int t = threadIdx.x;
    #pragma unroll
    for (int i = 0; i < 4; ++i) {
        int f = t + 256 * i;
        int j = f >> 5, r = f & 31;
        bfrag v;
        #pragma unroll
        for (int e = 0; e < 8; ++e) {
            int k = j * 8 + e;
            v[e] = f2bf(W1[(size_t)k * DH + 32 * c + r] * g[k]);
        }
        *(bfrag*)(dst + (size_t)c * 8192 + (size_t)f * 8) = v;
    }
}

// W2 transpose+cast: dst[o][h] = bf16(W2[h][o])
__global__ void tcast(const float* __restrict__ src, short* __restrict__ dst,
                      int R, int C) {
    __shared__ short t[64][67];
    const int c0 = blockIdx.x * 64, r0 = blockIdx.y * 64;
    const int lr = threadIdx.x >> 6, lc = threadIdx.x & 63;
    #pragma unroll
    for (int i = 0; i < 16; ++i) {
        int row = i * 4 + lr;
        t[row][lc] = f2bf(src[(size_t)(r0 + row) * C + c0 + lc]);
    }
    __syncthreads();
    #pragma unroll
    for (int i = 0; i < 16; ++i) {
        int row = i * 4 + lr;
        dst[(size_t)(c0 + row) * R + r0 + lc] = t[lc][row];
    }
}

// b1p[n] = b1[n] + sum_k beta[k] * W1[k][n]
__global__ void b1prep(const float* __restrict__ W1, const float* __restrict__ b1,
                       const float* __restrict__ beta, float* __restrict__ b1p) {
    int n = blockIdx.x * 256 + threadIdx.x;
    float acc = b1[n];
    for (int k = 0; k < DIN; ++k) acc += beta[k] * W1[(size_t)k * DH + n];
    b1p[n] = acc;
}

// LN halves: load 16 rows' worth (one row per (l16) x 8 k-blocks), keep bf16 copy
// in-place in the destination frag array; stats in f32.
__device__ __forceinline__ void ln_load_rf(const float* __restrict__ xr,
                                           bfrag* dst, float& sum_o, float& ssq_o) {
    float sum = 0.f, ssq = 0.f;
    #pragma unroll
    for (int k2 = 0; k2 < 8; ++k2) {
        f4v xa = __builtin_nontemporal_load((const f4v*)(xr + k2 * 32));
        f4v xc = __builtin_nontemporal_load((const f4v*)(xr + k2 * 32 + 4));
        bfrag t;
        #pragma unroll
        for (int j = 0; j < 4; ++j) {
            sum += xa[j] + xc[j];
            ssq = fmaf(xa[j], xa[j], fmaf(xc[j], xc[j], ssq));
            t[j]     = f2bf(xa[j]);
            t[j + 4] = f2bf(xc[j]);
        }
        dst[k2] = t;
    }
    sum_o = sum; ssq_o = ssq;
}

__device__ __forceinline__ void ln_finish_rf(bfrag* x8, float sum, float ssq) {
    sum += __shfl_xor(sum, 16); sum += __shfl_xor(sum, 32);
    ssq += __shfl_xor(ssq, 16); ssq += __shfl_xor(ssq, 32);
    float mean = sum * (1.f / 256.f);
    float var = ssq * (1.f / 256.f) - mean * mean;
    float rstd = rsqrtf(var + 1e-5f);
    #pragma unroll
    for (int kb = 0; kb < 8; ++kb) {
        bfrag t = x8[kb];
        #pragma unroll
        for (int j = 0; j < 8; ++j) t[j] = f2bf((bf2f(t[j]) - mean) * rstd);
        x8[kb] = t;
    }
}

// Per set: h_s = relu(LN(x_s)@W1 + b1'); feat = h_s@W2 + b2 (AGPR accumulators);
// score from feat; online softmax in output domain: agg = al*agg + pp*feat.
// out = feat_local + agg / l.
__global__ __launch_bounds__(512) __attribute__((amdgpu_waves_per_eu(2, 2)))
void fused_node(const float* __restrict__ state, const float* __restrict__ nbr,
                const float* __restrict__ b1p, const float* __restrict__ b2,
                const float* __restrict__ aw, const float* __restrict__ ab,
                const short* __restrict__ w1t, const short* __restrict__ w2t,
                float* __restrict__ out) {
    __shared__ short h_all[8 * 128 * 72];   // 147456 B: [pair][row][72] (2 chunks/pair)
    __shared__ float b1_lds[DH];            // 2048
    __shared__ float scorep[4 * MROWS];     // 2048
    __shared__ float m_lds[MROWS], l_lds[MROWS], al_lds[MROWS], pp_lds[MROWS], il_lds[MROWS];
    // total 154112 B -> 1 block/CU, 8 waves (2/SIMD)

    const int tid = threadIdx.x;
    const int wv = tid >> 6, lane = tid & 63;
    const int q = lane >> 4, l16 = lane & 15;
    const int rg2 = wv >> 1, cg = wv & 1;     // stage1 grid: 4 row-groups x 2 col-halves
    const int rg  = wv >> 2, cg2 = wv & 3;    // GEMM2 grid: 2 row-groups x 4 col-groups
    const int row0 = blockIdx.x * MROWS;

    b1_lds[tid] = b1p[tid];
    if (tid < MROWS) { m_lds[tid] = -__builtin_huge_valf(); l_lds[tid] = 0.f; }

    float b2v[4], awv[4];
    #pragma unroll
    for (int ct = 0; ct < 4; ++ct) {
        b2v[ct] = b2[64 * cg2 + 16 * ct + l16];
        awv[ct] = aw[64 * cg2 + 16 * ct + l16];
    }
    const float attnb = ab[0];

    // stage1 store geometry: col-group XOR'd with q ((row>>2)&3 == q for our rows)
    const int cw  = (((2 * cg + (l16 >> 3)) ^ q) << 3) | (l16 & 7);
    const int rb1 = 32 * rg2 + 4 * q;
    const short* wbase = w1t + (16 * cg + l16) * 8 + q * 256;
    // GEMM2 read geometry: reader key (row>>2)&3 == (l16>>2)
    const int arow = 64 * rg + l16;
    const int akx  = (q ^ (l16 >> 2)) << 3;

    ffrag agg[4][4];
    #pragma unroll
    for (int mt = 0; mt < 4; ++mt)
        #pragma unroll
        for (int ct = 0; ct < 4; ++ct) { ffrag z = {0.f, 0.f, 0.f, 0.f}; agg[mt][ct] = z; }

    bfrag xnf[2][8];
    float sums[2], ssqs[2];
    ffrag feat[4][4];

    // ---- prologue: LN of set 0 ----
    {
        const float* xb = nbr + (size_t)row0 * DIN;   // s = 0
        ln_load_rf(xb + (size_t)(32 * rg2 + l16) * DIN + q * 8, xnf[0], sums[0], ssqs[0]);
        ln_load_rf(xb + (size_t)(32 * rg2 + 16 + l16) * DIN + q * 8, xnf[1], sums[1], ssqs[1]);
        ln_finish_rf(xnf[0], sums[0], ssqs[0]);
        ln_finish_rf(xnf[1], sums[1], ssqs[1]);
    }
    __syncthreads();   // b1_lds / softmax init visible

    for (int s = 0; s <= NNB; ++s) {
        #pragma unroll
        for (int mt = 0; mt < 4; ++mt)
            #pragma unroll
            for (int ct = 0; ct < 4; ++ct) {
                ffrag fi = {b2v[ct], b2v[ct], b2v[ct], b2v[ct]};
                feat[mt][ct] = fi;
            }
        // ---- stage1: h = xn @ W1 + b1', relu -> h_all. W1 from global (L1). ----
        for (int c = 0; c < NCHUNK; ++c) {
            const short* wp = wbase + c * 8192;
            const float bb = b1_lds[c * 32 + 16 * cg + l16];
            ffrag h0 = {bb, bb, bb, bb}, h1 = {bb, bb, bb, bb};
            #pragma unroll
            for (int kb = 0; kb < 8; ++kb) {
                bfrag w = *(const bfrag*)(wp + kb * 1024);
                h0 = __builtin_amdgcn_mfma_f32_16x16x32_bf16(xnf[0][kb], w, h0, 0, 0, 0);
                h1 = __builtin_amdgcn_mfma_f32_16x16x32_bf16(xnf[1][kb], w, h1, 0, 0, 0);
            }
            short* hp = h_all + (c >> 1) * 9216 + (c & 1) * 32 + cw;
            #pragma unroll
            for (int r = 0; r < 4; ++r) {
                hp[(rb1 + r) * 72]      = f2bf(fmaxf(h0[r], 0.f));
                hp[(rb1 + 16 + r) * 72] = f2bf(fmaxf(h1[r], 0.f));
            }
        }
        __syncthreads();   // B1: h_all complete

        const bool more = (s < NNB);
        const float* xbn = nullptr;
        if (more) {   // prefetch half of next set's LN into dead xnf[0]
            xbn = (s + 1 == NNB) ? (state + (size_t)row0 * DIN)
                                 : (nbr + ((size_t)(s + 1) * BROWS + (size_t)row0) * DIN);
            ln_load_rf(xbn + (size_t)(32 * rg2 + l16) * DIN + q * 8, xnf[0], sums[0], ssqs[0]);
        }

        // ---- GEMM2: feat += h @ W2 (A from h_all, B from global w2t) ----
        for (int c = 0; c < NCHUNK; ++c) {
            const short* hq = h_all + (c >> 1) * 9216 + (c & 1) * 32 + akx;
            bfrag af[4], bfr[4];
            #pragma unroll
            for (int mt = 0; mt < 4; ++mt)
                af[mt] = *(const bfrag*)(hq + (arow + 16 * mt) * 72);
            #pragma unroll
            for (int ct = 0; ct < 4; ++ct)
                bfr[ct] = *(const bfrag*)(w2t + (size_t)(64 * cg2 + 16 * ct + l16) * DH + c * 32 + q * 8);
            #pragma unroll
            for (int mt = 0; mt < 4; ++mt)
                #pragma unroll
                for (int ct = 0; ct < 4; ++ct)
                    feat[mt][ct] = __builtin_amdgcn_mfma_f32_16x16x32_bf16(af[mt], bfr[ct], feat[mt][ct], 0, 0, 0);
        }

        if (more) {
            ln_load_rf(xbn + (size_t)(32 * rg2 + 16 + l16) * DIN + q * 8, xnf[1], sums[1], ssqs[1]);
            // ---- score from feat: sc[row] = sum_col feat*aw ----
            float sp[4][4];
            #pragma unroll
            for (int mt = 0; mt < 4; ++mt)
                #pragma unroll
                for (int r = 0; r < 4; ++r) {
                    float vv = feat[mt][0][r] * awv[0] + feat[mt][1][r] * awv[1]
                             + feat[mt][2][r] * awv[2] + feat[mt][3][r] * awv[3];
                    vv += __shfl_xor(vv, 1); vv += __shfl_xor(vv, 2);
                    vv += __shfl_xor(vv, 4); vv += __shfl_xor(vv, 8);
                    sp[mt][r] = vv;
                }
            if (l16 == 0) {
                #pragma unroll
                for (int mt = 0; mt < 4; ++mt)
                    #pragma unroll
                    for (int r = 0; r < 4; ++r)
                        scorep[cg2 * MROWS + 64 * rg + 16 * mt + 4 * q + r] = sp[mt][r];
            }
            __syncthreads();   // B2
            if (tid < MROWS) {
                float sc = scorep[tid] + scorep[MROWS + tid] + scorep[2 * MROWS + tid]
                         + scorep[3 * MROWS + tid] + attnb;
                float mo = m_lds[tid];
                float mn = fmaxf(mo, sc);
                float al = __expf(mo - mn);
                float pp = __expf(sc - mn);
                float ln = l_lds[tid] * al + pp;
                m_lds[tid] = mn; l_lds[tid] = ln;
                al_lds[tid] = al; pp_lds[tid] = pp;
                if (s == NNB - 1) il_lds[tid] = 1.f / ln;
            }
            __syncthreads();   // B3
            // ---- agg = al*agg + pp*feat (AGPR-domain online softmax) ----
            #pragma unroll
            for (int mt = 0; mt < 4; ++mt) {
                float alv[4], ppv[4];
                #pragma unroll
                for (int r = 0; r < 4; ++r) {
                    int rr = 64 * rg + 16 * mt + 4 * q + r;
                    alv[r] = al_lds[rr]; ppv[r] = pp_lds[rr];
                }
                #pragma unroll
                for (int ct = 0; ct < 4; ++ct)
                    #pragma unroll
                    for (int r = 0; r < 4; ++r)
                        agg[mt][ct][r] = agg[mt][ct][r] * alv[r] + ppv[r] * feat[mt][ct][r];
            }
            // finish next set's LN (in place)
            ln_finish_rf(xnf[0], sums[0], ssqs[0]);
            ln_finish_rf(xnf[1], sums[1], ssqs[1]);
        }
    }

    // ---- epilogue: out = feat_local + agg / l ----
    #pragma unroll
    for (int mt = 0; mt < 4; ++mt)
        #pragma unroll
        for (int r = 0; r < 4; ++r) {
            int row = 64 * rg + 16 * mt + 4 * q + r;
            float il = il_lds[row];
            size_t base = (size_t)(row0 + row) * DOUT + 64 * cg2 + l16;
            #pragma unroll
            for (int ct = 0; ct < 4; ++ct)
                __builtin_nontemporal_store(feat[mt][ct][r] + agg[mt][ct][r] * il,
                                            out + base + ct * 16);
        }
}

extern "C" void kernel_launch(void* const* d_in, const int* in_sizes, int n_in,
                              void* d_out, int out_size, void* d_ws, size_t ws_size,
                              hipStream_t stream) {
    const float* state = (const float*)d_in[0];
    const float* nbr   = (const float*)d_in[1];
    const float* gamma = (const float*)d_in[2];
    const float* beta  = (const float*)d_in[3];
    const float* W1    = (const float*)d_in[4];
    const float* b1    = (const float*)d_in[5];
    const float* W2    = (const float*)d_in[6];
    const float* b2    = (const float*)d_in[7];
    const float* aw    = (const float*)d_in[8];
    const float* ab    = (const float*)d_in[9];
    float* out = (float*)d_out;

    short* w1t = (short*)d_ws;                       // [16 chunks][1024 frags][8] bf16
    short* w2t = w1t + (size_t)DH * DIN;             // [256][512] bf16
    float* b1p = (float*)(w2t + (size_t)DOUT * DH);  // [512] fp32 (beta-folded)

    w1prep<<<NCHUNK, 256, 0, stream>>>(W1, gamma, w1t);
    tcast<<<dim3(DOUT / 64, DH / 64), 256, 0, stream>>>(W2, w2t, DH, DOUT);
    b1prep<<<2, 256, 0, stream>>>(W1, b1, beta, b1p);
    fused_node<<<BROWS / MROWS, 512, 0, stream>>>(state, nbr, b1p, b2, aw, ab,
                                                  w1t, w2t, out);
}